// Round 7
// baseline (219.855 us; speedup 1.0000x reference)
//
#include <hip/hip_runtime.h>

#define WIN 7
constexpr int H = 512, W = 512;
constexpr int OH = H - WIN + 1;   // 506
constexpr int OW = W - WIN + 1;   // 506
constexpr float INV_NP = 1.0f / 49.0f;
constexpr float COV_NORM = 49.0f / 48.0f;

#define TW 256   // output columns per block (== blockDim.x)
#define RT 64    // output rows per block tile
#define SEGS 16  // blocks per batch image in the max kernel

// ---------------- Kernel 1: per-batch max of |Y| ----------------
// 16 blocks per batch (1024 total) so the scan saturates all 256 CUs.
// Per-batch combine via atomicMax on the int bit-pattern (valid: |Y| >= 0,
// and the 0xAA poison in d_ws is negative as int, so it always loses).
__global__ __launch_bounds__(256) void batch_max_kernel(const float* __restrict__ Y,
                                                        float* __restrict__ maxv,
                                                        float* __restrict__ out) {
    const int b   = blockIdx.x >> 4;          // batch
    const int seg = blockIdx.x & (SEGS - 1);  // segment within image
    constexpr int SEG_F4 = H * W / SEGS / 4;  // float4s per segment (16384)
    const float4* p = (const float4*)(Y + (size_t)b * H * W) + (size_t)seg * SEG_F4;
    float m = 0.f;
    #pragma unroll 4
    for (int i = threadIdx.x; i < SEG_F4; i += 256) {
        float4 v = p[i];
        m = fmaxf(m, fmaxf(fmaxf(fabsf(v.x), fabsf(v.y)),
                           fmaxf(fabsf(v.z), fabsf(v.w))));
    }
    #pragma unroll
    for (int off = 32; off > 0; off >>= 1)
        m = fmaxf(m, __shfl_down(m, off, 64));
    __shared__ float smax[4];
    const int wave = threadIdx.x >> 6;
    const int lane = threadIdx.x & 63;
    if (lane == 0) smax[wave] = m;
    __syncthreads();
    if (threadIdx.x == 0) {
        const float bm = fmaxf(fmaxf(smax[0], smax[1]), fmaxf(smax[2], smax[3]));
        atomicMax((int*)&maxv[b], __float_as_int(bm));
        if (blockIdx.x == 0) out[0] = 0.f;    // d_out is poisoned with 0xAA
    }
}

// ---------------- Kernel 2: fused box moments + SSIM + mean ----------------
__global__ __launch_bounds__(256) void ssim_kernel(const float* __restrict__ X,
                                                   const float* __restrict__ Y,
                                                   const float* __restrict__ maxv,
                                                   float* __restrict__ out,
                                                   float inv_total) {
    const int b    = blockIdx.z;
    const int col0 = blockIdx.x * TW;
    const int r0   = blockIdx.y * RT;
    const int nr   = min(RT, OH - r0);           // output rows this block
    const int nri  = nr + WIN - 1;               // input rows needed
    const int ncols = min(TW + WIN - 1, W - col0);

    const float mv = maxv[b];
    const float C1 = (0.01f * mv) * (0.01f * mv);
    const float C2 = (0.03f * mv) * (0.03f * mv);

    const size_t base = (size_t)b * H * W;
    const float* Xb = X + base;
    const float* Yb = Y + base;

    __shared__ float2 lds[WIN][TW + WIN - 1];    // 7 x 262 float2 = 14.7 KB

    const int tid = threadIdx.x;
    const bool active = (col0 + tid) < OW;

    float ring_x[WIN], ring_y[WIN], ring_xx[WIN], ring_yy[WIN], ring_xy[WIN];
    #pragma unroll
    for (int k = 0; k < WIN; ++k) {
        ring_x[k] = 0.f; ring_y[k] = 0.f; ring_xx[k] = 0.f;
        ring_yy[k] = 0.f; ring_xy[k] = 0.f;
    }
    float vs_x = 0.f, vs_y = 0.f, vs_xx = 0.f, vs_yy = 0.f, vs_xy = 0.f;
    float acc = 0.f;

    for (int t = 0; t < nri; t += WIN) {
        const int nrows_chunk = min(WIN, nri - t);   // block-uniform
        // stage chunk of up to 7 input rows into LDS as (x, |y|)
        for (int r = 0; r < nrows_chunk; ++r) {
            const int gr = r0 + t + r;
            const float* xrow = Xb + (size_t)gr * W + col0;
            const float* yrow = Yb + (size_t)gr * W + col0;
            for (int c = tid; c < TW + WIN - 1; c += 256) {
                float xv = 0.f, yv = 0.f;
                if (c < ncols) { xv = xrow[c]; yv = fabsf(yrow[c]); }
                lds[r][c] = make_float2(xv, yv);
            }
        }
        __syncthreads();
        #pragma unroll
        for (int k = 0; k < WIN; ++k) {          // k is compile-time -> ring regs stay in VGPRs
            if (k < nrows_chunk) {               // block-uniform condition
                const int tt = t + k;            // tt % 7 == k (t is a multiple of 7)
                float hx = 0.f, hy = 0.f, hxx = 0.f, hyy = 0.f, hxy = 0.f;
                #pragma unroll
                for (int j = 0; j < WIN; ++j) {
                    float2 v = lds[k][tid + j];
                    hx += v.x;
                    hy += v.y;
                    hxx = fmaf(v.x, v.x, hxx);
                    hyy = fmaf(v.y, v.y, hyy);
                    hxy = fmaf(v.x, v.y, hxy);
                }
                vs_x  += hx  - ring_x[k];  ring_x[k]  = hx;
                vs_y  += hy  - ring_y[k];  ring_y[k]  = hy;
                vs_xx += hxx - ring_xx[k]; ring_xx[k] = hxx;
                vs_yy += hyy - ring_yy[k]; ring_yy[k] = hyy;
                vs_xy += hxy - ring_xy[k]; ring_xy[k] = hxy;
                if (tt >= WIN - 1 && active) {
                    const float ux  = vs_x  * INV_NP;
                    const float uy  = vs_y  * INV_NP;
                    const float uxx = vs_xx * INV_NP;
                    const float uyy = vs_yy * INV_NP;
                    const float uxy = vs_xy * INV_NP;
                    const float vx  = COV_NORM * (uxx - ux * ux);
                    const float vy  = COV_NORM * (uyy - uy * uy);
                    const float vxy = COV_NORM * (uxy - ux * uy);
                    const float A1 = 2.f * ux * uy + C1;
                    const float A2 = 2.f * vxy + C2;
                    const float B1 = ux * ux + uy * uy + C1;
                    const float B2 = vx + vy + C2;
                    const float S = (A1 * A2) / (B1 * B2);
                    acc += 1.f - S;
                }
            }
        }
        __syncthreads();
    }

    // block reduction -> one atomicAdd per block
    acc *= inv_total;
    #pragma unroll
    for (int off = 32; off > 0; off >>= 1)
        acc += __shfl_down(acc, off, 64);
    __shared__ float sacc[4];
    const int wave = tid >> 6;
    const int lane = tid & 63;
    if (lane == 0) sacc[wave] = acc;
    __syncthreads();
    if (tid == 0)
        atomicAdd(out, sacc[0] + sacc[1] + sacc[2] + sacc[3]);
}

extern "C" void kernel_launch(void* const* d_in, const int* in_sizes, int n_in,
                              void* d_out, int out_size, void* d_ws, size_t ws_size,
                              hipStream_t stream) {
    const float* X = (const float*)d_in[0];
    const float* Y = (const float*)d_in[1];
    float* out  = (float*)d_out;
    float* maxv = (float*)d_ws;
    const int B = in_sizes[0] / (H * W);

    batch_max_kernel<<<B * SEGS, 256, 0, stream>>>(Y, maxv, out);

    dim3 grid((OW + TW - 1) / TW, (OH + RT - 1) / RT, B);
    const float inv_total = 1.0f / ((float)B * (float)OW * (float)OH);
    ssim_kernel<<<grid, 256, 0, stream>>>(X, Y, maxv, out, inv_total);
}

// Round 8
// 219.254 us; speedup vs baseline: 1.0027x; 1.0027x over previous
//
#include <hip/hip_runtime.h>

#define WIN 7
constexpr int H = 512, W = 512;
constexpr int OH = H - WIN + 1;   // 506
constexpr int OW = W - WIN + 1;   // 506
constexpr float INV_NP = 1.0f / 49.0f;
constexpr float COV_NORM = 49.0f / 48.0f;

#define TW 256   // output columns per block (== blockDim.x)
#define RT 32    // output rows per block tile (32 -> 2048 blocks -> 8 blocks/CU)
#define SEGS 16  // blocks per batch image in the max kernel

// ---------------- Kernel 1: per-batch max of |Y| ----------------
// 16 blocks per batch (1024 total) so the scan saturates all 256 CUs.
// Per-batch combine via atomicMax on the int bit-pattern (valid: |Y| >= 0,
// and the 0xAA poison in d_ws is negative as int, so it always loses).
__global__ __launch_bounds__(256) void batch_max_kernel(const float* __restrict__ Y,
                                                        float* __restrict__ maxv,
                                                        float* __restrict__ out) {
    const int b   = blockIdx.x >> 4;          // batch
    const int seg = blockIdx.x & (SEGS - 1);  // segment within image
    constexpr int SEG_F4 = H * W / SEGS / 4;  // float4s per segment (4096)
    const float4* p = (const float4*)(Y + (size_t)b * H * W) + (size_t)seg * SEG_F4;
    float m = 0.f;
    #pragma unroll 4
    for (int i = threadIdx.x; i < SEG_F4; i += 256) {
        float4 v = p[i];
        m = fmaxf(m, fmaxf(fmaxf(fabsf(v.x), fabsf(v.y)),
                           fmaxf(fabsf(v.z), fabsf(v.w))));
    }
    #pragma unroll
    for (int off = 32; off > 0; off >>= 1)
        m = fmaxf(m, __shfl_down(m, off, 64));
    __shared__ float smax[4];
    const int wave = threadIdx.x >> 6;
    const int lane = threadIdx.x & 63;
    if (lane == 0) smax[wave] = m;
    __syncthreads();
    if (threadIdx.x == 0) {
        const float bm = fmaxf(fmaxf(smax[0], smax[1]), fmaxf(smax[2], smax[3]));
        atomicMax((int*)&maxv[b], __float_as_int(bm));
        if (blockIdx.x == 0) out[0] = 0.f;    // d_out is poisoned with 0xAA
    }
}

// ---------------- Kernel 2: fused box moments + SSIM + mean ----------------
__global__ __launch_bounds__(256) void ssim_kernel(const float* __restrict__ X,
                                                   const float* __restrict__ Y,
                                                   const float* __restrict__ maxv,
                                                   float* __restrict__ out,
                                                   float inv_total) {
    const int b    = blockIdx.z;
    const int col0 = blockIdx.x * TW;
    const int r0   = blockIdx.y * RT;
    const int nr   = min(RT, OH - r0);           // output rows this block
    const int nri  = nr + WIN - 1;               // input rows needed
    const int ncols = min(TW + WIN - 1, W - col0);

    const float mv = maxv[b];
    const float C1 = (0.01f * mv) * (0.01f * mv);
    const float C2 = (0.03f * mv) * (0.03f * mv);

    const size_t base = (size_t)b * H * W;
    const float* Xb = X + base;
    const float* Yb = Y + base;

    __shared__ float2 lds[WIN][TW + WIN - 1];    // 7 x 262 float2 = 14.7 KB

    const int tid = threadIdx.x;
    const bool active = (col0 + tid) < OW;

    float ring_x[WIN], ring_y[WIN], ring_xx[WIN], ring_yy[WIN], ring_xy[WIN];
    #pragma unroll
    for (int k = 0; k < WIN; ++k) {
        ring_x[k] = 0.f; ring_y[k] = 0.f; ring_xx[k] = 0.f;
        ring_yy[k] = 0.f; ring_xy[k] = 0.f;
    }
    float vs_x = 0.f, vs_y = 0.f, vs_xx = 0.f, vs_yy = 0.f, vs_xy = 0.f;
    float acc = 0.f;

    for (int t = 0; t < nri; t += WIN) {
        const int nrows_chunk = min(WIN, nri - t);   // block-uniform
        // stage chunk of up to 7 input rows into LDS as (x, |y|)
        for (int r = 0; r < nrows_chunk; ++r) {
            const int gr = r0 + t + r;
            const float* xrow = Xb + (size_t)gr * W + col0;
            const float* yrow = Yb + (size_t)gr * W + col0;
            for (int c = tid; c < TW + WIN - 1; c += 256) {
                float xv = 0.f, yv = 0.f;
                if (c < ncols) { xv = xrow[c]; yv = fabsf(yrow[c]); }
                lds[r][c] = make_float2(xv, yv);
            }
        }
        __syncthreads();
        #pragma unroll
        for (int k = 0; k < WIN; ++k) {          // k is compile-time -> ring regs stay in VGPRs
            if (k < nrows_chunk) {               // block-uniform condition
                const int tt = t + k;            // tt % 7 == k (t is a multiple of 7)
                float hx = 0.f, hy = 0.f, hxx = 0.f, hyy = 0.f, hxy = 0.f;
                #pragma unroll
                for (int j = 0; j < WIN; ++j) {
                    float2 v = lds[k][tid + j];
                    hx += v.x;
                    hy += v.y;
                    hxx = fmaf(v.x, v.x, hxx);
                    hyy = fmaf(v.y, v.y, hyy);
                    hxy = fmaf(v.x, v.y, hxy);
                }
                vs_x  += hx  - ring_x[k];  ring_x[k]  = hx;
                vs_y  += hy  - ring_y[k];  ring_y[k]  = hy;
                vs_xx += hxx - ring_xx[k]; ring_xx[k] = hxx;
                vs_yy += hyy - ring_yy[k]; ring_yy[k] = hyy;
                vs_xy += hxy - ring_xy[k]; ring_xy[k] = hxy;
                if (tt >= WIN - 1 && active) {
                    const float ux  = vs_x  * INV_NP;
                    const float uy  = vs_y  * INV_NP;
                    const float uxx = vs_xx * INV_NP;
                    const float uyy = vs_yy * INV_NP;
                    const float uxy = vs_xy * INV_NP;
                    const float vx  = COV_NORM * (uxx - ux * ux);
                    const float vy  = COV_NORM * (uyy - uy * uy);
                    const float vxy = COV_NORM * (uxy - ux * uy);
                    const float A1 = 2.f * ux * uy + C1;
                    const float A2 = 2.f * vxy + C2;
                    const float B1 = ux * ux + uy * uy + C1;
                    const float B2 = vx + vy + C2;
                    // fast reciprocal: rel err ~1e-6, threshold is 2e-2 -> safe
                    const float S = (A1 * A2) * __builtin_amdgcn_rcpf(B1 * B2);
                    acc += 1.f - S;
                }
            }
        }
        __syncthreads();
    }

    // block reduction -> one atomicAdd per block
    acc *= inv_total;
    #pragma unroll
    for (int off = 32; off > 0; off >>= 1)
        acc += __shfl_down(acc, off, 64);
    __shared__ float sacc[4];
    const int wave = tid >> 6;
    const int lane = tid & 63;
    if (lane == 0) sacc[wave] = acc;
    __syncthreads();
    if (tid == 0)
        atomicAdd(out, sacc[0] + sacc[1] + sacc[2] + sacc[3]);
}

extern "C" void kernel_launch(void* const* d_in, const int* in_sizes, int n_in,
                              void* d_out, int out_size, void* d_ws, size_t ws_size,
                              hipStream_t stream) {
    const float* X = (const float*)d_in[0];
    const float* Y = (const float*)d_in[1];
    float* out  = (float*)d_out;
    float* maxv = (float*)d_ws;
    const int B = in_sizes[0] / (H * W);

    batch_max_kernel<<<B * SEGS, 256, 0, stream>>>(Y, maxv, out);

    dim3 grid((OW + TW - 1) / TW, (OH + RT - 1) / RT, B);
    const float inv_total = 1.0f / ((float)B * (float)OW * (float)OH);
    ssim_kernel<<<grid, 256, 0, stream>>>(X, Y, maxv, out, inv_total);
}

// Round 9
// 186.474 us; speedup vs baseline: 1.1790x; 1.1758x over previous
//
#include <hip/hip_runtime.h>

#define WIN 7
constexpr int H = 512, W = 512;
constexpr int OH = H - WIN + 1;   // 506
constexpr int OW = W - WIN + 1;   // 506
constexpr float INV_NP = 1.0f / 49.0f;
constexpr float COV_NORM = 49.0f / 48.0f;

#define SEGS 16  // blocks per batch image in the max kernel

// ---------------- Kernel 1: per-batch max of |Y| ----------------
__global__ __launch_bounds__(256) void batch_max_kernel(const float* __restrict__ Y,
                                                        float* __restrict__ maxv,
                                                        float* __restrict__ out) {
    const int b   = blockIdx.x >> 4;
    const int seg = blockIdx.x & (SEGS - 1);
    constexpr int SEG_F4 = H * W / SEGS / 4;
    const float4* p = (const float4*)(Y + (size_t)b * H * W) + (size_t)seg * SEG_F4;
    float m = 0.f;
    #pragma unroll 4
    for (int i = threadIdx.x; i < SEG_F4; i += 256) {
        float4 v = p[i];
        m = fmaxf(m, fmaxf(fmaxf(fabsf(v.x), fabsf(v.y)),
                           fmaxf(fabsf(v.z), fabsf(v.w))));
    }
    #pragma unroll
    for (int off = 32; off > 0; off >>= 1)
        m = fmaxf(m, __shfl_down(m, off, 64));
    __shared__ float smax[4];
    const int wave = threadIdx.x >> 6;
    const int lane = threadIdx.x & 63;
    if (lane == 0) smax[wave] = m;
    __syncthreads();
    if (threadIdx.x == 0) {
        const float bm = fmaxf(fmaxf(smax[0], smax[1]), fmaxf(smax[2], smax[3]));
        atomicMax((int*)&maxv[b], __float_as_int(bm));
        if (blockIdx.x == 0) out[0] = 0.f;    // d_out is poisoned with 0xAA
    }
}

// ---------------- Kernel 2: wave-autonomous fused SSIM ----------------
// Each WAVE owns a 64-col x 64-row output tile. No __syncthreads in the
// main loop: per row-step the wave stages one input row into its private
// LDS row buffer (wave-coherent ds_write -> ds_read), prefetches the next
// row's global loads into registers, computes horizontal 7-sums, and
// slides the vertical window via a compile-time register ring.
__global__ __launch_bounds__(256, 4) void ssim_kernel(const float* __restrict__ X,
                                                      const float* __restrict__ Y,
                                                      const float* __restrict__ maxv,
                                                      float* __restrict__ out,
                                                      float inv_total) {
    const int wid  = threadIdx.x >> 6;
    const int lane = threadIdx.x & 63;
    const int span = blockIdx.x * 4 + wid;        // 0..7 column span
    const int col0 = span * 64;                   // 0..448
    const int r0   = blockIdx.y * 64;             // 0..448
    const int b    = blockIdx.z;
    const int nout = min(64, OH - r0);            // 64 (or 58 on last tile)
    const int nri  = nout + WIN - 1;              // input rows: 70 or 64
    const bool active = (col0 + lane) < OW;

    const float mv = maxv[b];
    const float C1 = (0.01f * mv) * (0.01f * mv);
    const float C2 = (0.03f * mv) * (0.03f * mv);

    __shared__ float2 rowbuf[4][72];              // per-wave 70-entry row buffer
    float2* rb = rowbuf[wid];

    const size_t base = (size_t)b * H * W;
    const int g1 = col0 + lane;                   // always < 512
    const bool t2 = (lane < 6) && (col0 + 64 + lane) < W;  // tail staging lanes

    const float* xp = X + base + (size_t)r0 * W + g1;
    const float* yp = Y + base + (size_t)r0 * W + g1;

    float ring_x[WIN], ring_y[WIN], ring_xx[WIN], ring_yy[WIN], ring_xy[WIN];
    #pragma unroll
    for (int k = 0; k < WIN; ++k) {
        ring_x[k] = 0.f; ring_y[k] = 0.f; ring_xx[k] = 0.f;
        ring_yy[k] = 0.f; ring_xy[k] = 0.f;
    }
    float vs_x = 0.f, vs_y = 0.f, vs_xx = 0.f, vs_yy = 0.f, vs_xy = 0.f;
    float acc = 0.f;

    // preload row 0 (tail via xp[64]: same row, +64 cols, valid iff t2)
    float x1n = xp[0], y1n = yp[0];
    float x2n = t2 ? xp[64] : 0.f, y2n = t2 ? yp[64] : 0.f;
    xp += W; yp += W;

    for (int t = 0; t < nri; t += WIN) {
        #pragma unroll
        for (int k = 0; k < WIN; ++k) {           // k compile-time: ring in VGPRs
            const int i = t + k;                  // i % 7 == k
            if (i < nri) {                        // wave-uniform
                // commit preloaded row i to LDS (abs applied to Y here)
                rb[lane] = make_float2(x1n, fabsf(y1n));
                if (lane < 6)
                    rb[64 + lane] = t2 ? make_float2(x2n, fabsf(y2n))
                                       : make_float2(0.f, 0.f);
                // prefetch row i+1 (latency hides under the compute below)
                if (i + 1 < nri) {                // wave-uniform
                    x1n = xp[0]; y1n = yp[0];
                    if (t2) { x2n = xp[64]; y2n = yp[64]; }
                    xp += W; yp += W;
                }
                // horizontal 7-sums of row i (reads just-written LDS;
                // compiler inserts the lgkmcnt wait — same-wave coherence)
                float hx = 0.f, hy = 0.f, hxx = 0.f, hyy = 0.f, hxy = 0.f;
                #pragma unroll
                for (int j = 0; j < WIN; ++j) {
                    float2 v = rb[lane + j];
                    hx += v.x;
                    hy += v.y;
                    hxx = fmaf(v.x, v.x, hxx);
                    hyy = fmaf(v.y, v.y, hyy);
                    hxy = fmaf(v.x, v.y, hxy);
                }
                vs_x  += hx  - ring_x[k];  ring_x[k]  = hx;
                vs_y  += hy  - ring_y[k];  ring_y[k]  = hy;
                vs_xx += hxx - ring_xx[k]; ring_xx[k] = hxx;
                vs_yy += hyy - ring_yy[k]; ring_yy[k] = hyy;
                vs_xy += hxy - ring_xy[k]; ring_xy[k] = hxy;
                if (i >= WIN - 1 && active) {
                    const float ux  = vs_x  * INV_NP;
                    const float uy  = vs_y  * INV_NP;
                    const float uxx = vs_xx * INV_NP;
                    const float uyy = vs_yy * INV_NP;
                    const float uxy = vs_xy * INV_NP;
                    const float vx  = COV_NORM * (uxx - ux * ux);
                    const float vy  = COV_NORM * (uyy - uy * uy);
                    const float vxy = COV_NORM * (uxy - ux * uy);
                    const float A1 = 2.f * ux * uy + C1;
                    const float A2 = 2.f * vxy + C2;
                    const float B1 = ux * ux + uy * uy + C1;
                    const float B2 = vx + vy + C2;
                    // fast reciprocal: rel err ~1e-6 vs 2e-2 threshold
                    const float S = (A1 * A2) * __builtin_amdgcn_rcpf(B1 * B2);
                    acc += 1.f - S;
                }
            }
        }
    }

    // wave reduce -> block reduce -> one atomicAdd per block
    acc *= inv_total;
    #pragma unroll
    for (int off = 32; off > 0; off >>= 1)
        acc += __shfl_down(acc, off, 64);
    __shared__ float sacc[4];
    if (lane == 0) sacc[wid] = acc;
    __syncthreads();
    if (threadIdx.x == 0)
        atomicAdd(out, sacc[0] + sacc[1] + sacc[2] + sacc[3]);
}

extern "C" void kernel_launch(void* const* d_in, const int* in_sizes, int n_in,
                              void* d_out, int out_size, void* d_ws, size_t ws_size,
                              hipStream_t stream) {
    const float* X = (const float*)d_in[0];
    const float* Y = (const float*)d_in[1];
    float* out  = (float*)d_out;
    float* maxv = (float*)d_ws;
    const int B = in_sizes[0] / (H * W);

    batch_max_kernel<<<B * SEGS, 256, 0, stream>>>(Y, maxv, out);

    // 8 col-spans (4 waves/block -> grid.x=2), 8 row tiles, B batches
    dim3 grid(2, 8, B);
    const float inv_total = 1.0f / ((float)B * (float)OW * (float)OH);
    ssim_kernel<<<grid, 256, 0, stream>>>(X, Y, maxv, out, inv_total);
}